// Round 6
// baseline (307.353 us; speedup 1.0000x reference)
//
#include <hip/hip_runtime.h>
#include <hip/hip_bf16.h>
#include <math.h>
#include <stdint.h>

#define N_NODES 40000
#define N_EDGES 640000
#define F_IN    512
#define F_OUT   32
#define HEADS   8
#define C_OUT   (HEADS * F_OUT)   // 256
#define NEG_SLOPE 0.2f
#define EPS_F   1e-16f

typedef __attribute__((ext_vector_type(8)))  short  short8;
typedef __attribute__((ext_vector_type(4)))  short  short4v;
typedef __attribute__((ext_vector_type(16))) float  float16v;

// truncating fp32 -> (hi,lo) bf16 split: hi+lo represents f to ~2^-17 rel
__device__ __forceinline__ void splitT(float f, unsigned short& hi, unsigned short& lo) {
    unsigned u = __float_as_uint(f);
    hi = (unsigned short)(u >> 16);
    float r = f - __uint_as_float(u & 0xFFFF0000u);
    lo = (unsigned short)(__float_as_uint(r) >> 16);
}

__device__ __forceinline__ unsigned short f2bf(float f) {
    unsigned u = __float_as_uint(f);
    return (unsigned short)((u + 0x7FFF + ((u >> 16) & 1)) >> 16);
}

// ---------------------------------------------------------------------------
// K0: pack W into per-lane B-fragment layout for mfma_f32_32x32x16_bf16.
// Bp[wc(4)][ktg(32)][ni(2)][lane(64)][j(8)], value =
//   B[k = ktg*16 + (lane>>5)*8 + j][col = wc*64 + ni*32 + (lane&31)]
// where B[k][col] = W[col>>5][k][col&31]. One wave dwordx4 per (kt,ni).
// ---------------------------------------------------------------------------
__global__ __launch_bounds__(256) void pack_W(const float* __restrict__ W,
                                              unsigned short* __restrict__ Bp) {
    int tid = blockIdx.x * 256 + threadIdx.x;   // 131072 total
    int j    = tid & 7;
    int L    = (tid >> 3) & 63;
    int ni   = (tid >> 9) & 1;
    int ktg  = (tid >> 10) & 31;
    int wc   = (tid >> 15) & 3;
    int k    = ktg * 16 + (L >> 5) * 8 + j;
    int col  = wc * 64 + ni * 32 + (L & 31);
    int hh = col >> 5, f = col & 31;
    Bp[tid] = f2bf(W[hh * (F_IN * F_OUT) + k * F_OUT + f]);
}

// ---------------------------------------------------------------------------
// K1: MFMA projection GEMM, 32x32x16 bf16, 2-term split ((x_hi+x_lo)*B_hi).
// Block: 8 waves (2 row x 4 col), tile 128x256; grid 313. BK=64, 8 stages.
// Software pipeline: per stage convert prefetched x regs -> LDS[buf], issue
// B-frag loads (L2), issue next stage's x loads, ONE barrier, MFMA.
// LDS double-buffered; A k-stride 33 dwords (conflict-free).
// ---------------------------------------------------------------------------
#define AS 66   // k-stride in shorts: 64 + 2 pad

__global__ __launch_bounds__(512, 2) void gemm_mfma(const float* __restrict__ x,
                                                    const unsigned short* __restrict__ Bp,
                                                    const float* __restrict__ a_src,
                                                    const float* __restrict__ a_dst,
                                                    unsigned short* __restrict__ h16,
                                                    float* __restrict__ s_src,
                                                    float* __restrict__ s_dst) {
    __shared__ unsigned short As_hi[2][128 * AS];
    __shared__ unsigned short As_lo[2][128 * AS];

    const int t = threadIdx.x;
    const int wave = t >> 6, L = t & 63;
    const int wr = wave & 1, wc = wave >> 1;      // 2 x 4 wave grid
    const int r31 = L & 31, half = L >> 5;
    const int n0 = blockIdx.x * 128;

    float16v acc[2][2];
#pragma unroll
    for (int i = 0; i < 2; ++i)
#pragma unroll
        for (int j = 0; j < 2; ++j)
#pragma unroll
            for (int r = 0; r < 16; ++r) acc[i][j][r] = 0.f;

    const int kcol = (t & 15) * 4;     // 0..60
    const int rbase = t >> 4;          // 0..31

    // row indices (clamped) for staging
    int rg[4];
#pragma unroll
    for (int it = 0; it < 4; ++it) {
        int r = n0 + rbase + it * 32;
        rg[it] = r < N_NODES ? r : N_NODES - 1;
    }

    float4 cur[4], nxt[4];
#pragma unroll
    for (int it = 0; it < 4; ++it)
        cur[it] = *(const float4*)&x[(size_t)rg[it] * F_IN + kcol];

#pragma unroll
    for (int st = 0; st < 8; ++st) {
        const int b = st & 1;
        // ---- convert cur -> LDS[b] ----
#pragma unroll
        for (int it = 0; it < 4; ++it) {
            unsigned short h0, h1, h2, h3, l0, l1, l2, l3;
            splitT(cur[it].x, h0, l0); splitT(cur[it].y, h1, l1);
            splitT(cur[it].z, h2, l2); splitT(cur[it].w, h3, l3);
            int off = (rbase + it * 32) * AS + kcol;
            *(short4v*)&As_hi[b][off] = (short4v){(short)h0, (short)h1, (short)h2, (short)h3};
            *(short4v*)&As_lo[b][off] = (short4v){(short)l0, (short)l1, (short)l2, (short)l3};
        }
        // ---- B fragments for this stage (L2-resident, issued before x) ----
        short8 breg[4][2];
#pragma unroll
        for (int kt = 0; kt < 4; ++kt)
#pragma unroll
            for (int ni = 0; ni < 2; ++ni) {
                size_t idx = ((((size_t)wc * 32 + (st * 4 + kt)) * 2 + ni) * 64 + L) * 8;
                breg[kt][ni] = *(const short8*)&Bp[idx];
            }
        // ---- prefetch next stage's x (newest in vmcnt queue) ----
        if (st < 7) {
#pragma unroll
            for (int it = 0; it < 4; ++it)
                nxt[it] = *(const float4*)&x[(size_t)rg[it] * F_IN + (st + 1) * 64 + kcol];
        }
        __syncthreads();
        // ---- MFMA ----
#pragma unroll
        for (int kt = 0; kt < 4; ++kt) {
            short8 ah[2], al[2];
#pragma unroll
            for (int mi = 0; mi < 2; ++mi) {
                int off = (wr * 64 + mi * 32 + r31) * AS + kt * 16 + half * 8;
                ah[mi] = *(const short8*)&As_hi[b][off];
                al[mi] = *(const short8*)&As_lo[b][off];
            }
#pragma unroll
            for (int mi = 0; mi < 2; ++mi)
#pragma unroll
                for (int ni = 0; ni < 2; ++ni) {
                    acc[mi][ni] = __builtin_amdgcn_mfma_f32_32x32x16_bf16(ah[mi], breg[kt][ni], acc[mi][ni], 0, 0, 0);
                    acc[mi][ni] = __builtin_amdgcn_mfma_f32_32x32x16_bf16(al[mi], breg[kt][ni], acc[mi][ni], 0, 0, 0);
                }
        }
        if (st < 7) {
#pragma unroll
            for (int it = 0; it < 4; ++it) cur[it] = nxt[it];
        }
    }

    // ---- epilogue 1: h16 stores ----
    // C/D layout (32x32): col = lane&31, row = (reg&3) + 8*(reg>>2) + 4*half
#pragma unroll
    for (int mi = 0; mi < 2; ++mi)
#pragma unroll
        for (int ni = 0; ni < 2; ++ni) {
            int colb = wc * 64 + ni * 32 + r31;
#pragma unroll
            for (int r = 0; r < 16; ++r) {
                int row = n0 + wr * 64 + mi * 32 + (r & 3) + 8 * (r >> 2) + 4 * half;
                if (row < N_NODES)
                    h16[(size_t)row * C_OUT + colb] = f2bf(acc[mi][ni][r]);
            }
        }

    // ---- epilogue 2: fused attention scores (fp32-exact) ----
    // ni-frag covers exactly one head: hh = wc*2 + ni
#pragma unroll
    for (int ni = 0; ni < 2; ++ni) {
        int hh = wc * 2 + ni;
        float af = a_src[hh * 32 + r31];
        float df = a_dst[hh * 32 + r31];
#pragma unroll
        for (int mi = 0; mi < 2; ++mi)
#pragma unroll
            for (int r = 0; r < 16; ++r) {
                float v = acc[mi][ni][r];
                float vs = v * af;
                float vd = v * df;
#pragma unroll
                for (int m = 1; m < 32; m <<= 1) {
                    vs += __shfl_xor(vs, m, 64);
                    vd += __shfl_xor(vd, m, 64);
                }
                if (r31 == 0) {
                    int row = n0 + wr * 64 + mi * 32 + (r & 3) + 8 * (r >> 2) + 4 * half;
                    if (row < N_NODES) {
                        s_src[row * 8 + hh] = vs;
                        s_dst[row * 8 + hh] = vd;
                    }
                }
            }
    }
}

// ---------------------------------------------------------------------------
// K3: per-dst in-degree counts
// ---------------------------------------------------------------------------
__global__ __launch_bounds__(256) void count_edges(const int* __restrict__ dst,
                                                   int* __restrict__ count) {
    int e = blockIdx.x * 256 + threadIdx.x;
    atomicAdd(&count[dst[e]], 1);
}

// ---------------------------------------------------------------------------
// K4a: 40-block local exclusive scan (1000/block) + per-block totals
// ---------------------------------------------------------------------------
__global__ __launch_bounds__(1024) void scan_local(const int* __restrict__ count,
                                                   int* __restrict__ row_excl,
                                                   int* __restrict__ cursor,
                                                   int* __restrict__ btot) {
    __shared__ int woff[16];
    __shared__ int tot_s;
    const int b = blockIdx.x, t = threadIdx.x;
    const int lane = t & 63, wid = t >> 6;
    const int i = b * 1000 + t;
    int v = (t < 1000) ? count[i] : 0;
    int inc = v;
#pragma unroll
    for (int d = 1; d < 64; d <<= 1) {
        int u = __shfl_up(inc, d, 64);
        if (lane >= d) inc += u;
    }
    if (lane == 63) woff[wid] = inc;
    __syncthreads();
    if (t < 16) {
        int s = woff[t];
        int sc = s;
#pragma unroll
        for (int d = 1; d < 16; d <<= 1) {
            int u = __shfl_up(sc, d, 64);
            if (t >= d) sc += u;
        }
        woff[t] = sc - s;
        if (t == 15) tot_s = sc;
    }
    __syncthreads();
    int excl = woff[wid] + inc - v;
    if (t < 1000) { row_excl[i] = excl; cursor[i] = excl; }
    if (t == 0) btot[b] = tot_s;
}

// K4b: exclusive scan of the 40 block totals -> boff
__global__ __launch_bounds__(64) void scan_tots(const int* __restrict__ btot,
                                                int* __restrict__ boff) {
    const int t = threadIdx.x;
    int v = (t < 40) ? btot[t] : 0;
    int inc = v;
#pragma unroll
    for (int d = 1; d < 64; d <<= 1) {
        int u = __shfl_up(inc, d, 64);
        if (t >= d) inc += u;
    }
    if (t < 40) boff[t] = inc - v;
}

// ---------------------------------------------------------------------------
// K5: slim scatter — only the dst-sorted src ids (4 B/edge).
// ---------------------------------------------------------------------------
__global__ __launch_bounds__(256) void scatter_edges(const int* __restrict__ src,
                                                     const int* __restrict__ dst,
                                                     int* __restrict__ cursor,
                                                     const int* __restrict__ boff,
                                                     int* __restrict__ src_sorted) {
    int e = blockIdx.x * 256 + threadIdx.x;
    int s = src[e], d = dst[e];
    int pos = atomicAdd(&cursor[d], 1) + boff[d / 1000];
    src_sorted[pos] = s;
}

// ---------------------------------------------------------------------------
// K6: aggregation. One WAVE per node; lane owns 4 channels; 4-edge unroll.
// w = exp(leaky(s_src[s]+s_dst[n])) recomputed inline (fp32 exact).
// ---------------------------------------------------------------------------
__global__ __launch_bounds__(256) void aggregate(const int* __restrict__ src_sorted,
                                                 const unsigned short* __restrict__ h16,
                                                 const float* __restrict__ s_src,
                                                 const float* __restrict__ s_dst,
                                                 const int* __restrict__ row_excl,
                                                 const int* __restrict__ boff,
                                                 const int* __restrict__ count,
                                                 const float* __restrict__ bias,
                                                 float* __restrict__ out) {
    const int t = threadIdx.x;
    const int wave = t >> 6, lane = t & 63;
    const int n = blockIdx.x * 4 + wave;
    const int ch0 = lane * 4;
    const int hh = lane >> 3;
    const int start = row_excl[n] + boff[n / 1000];
    const int cnt = count[n];
    const float sd = s_dst[n * 8 + hh];

    float a0 = 0.f, a1 = 0.f, a2 = 0.f, a3 = 0.f, den = 0.f;

    for (int base = 0; base < cnt; base += 4) {
        int rem = cnt - base;
        int idx = start + base;
        int s0 = src_sorted[idx];
        int s1 = (rem > 1) ? src_sorted[idx + 1] : 0;
        int s2 = (rem > 2) ? src_sorted[idx + 2] : 0;
        int s3 = (rem > 3) ? src_sorted[idx + 3] : 0;

        float e0 = s_src[s0 * 8 + hh] + sd;
        float e1 = s_src[s1 * 8 + hh] + sd;
        float e2 = s_src[s2 * 8 + hh] + sd;
        float e3 = s_src[s3 * 8 + hh] + sd;
        e0 = e0 >= 0.f ? e0 : NEG_SLOPE * e0;
        e1 = e1 >= 0.f ? e1 : NEG_SLOPE * e1;
        e2 = e2 >= 0.f ? e2 : NEG_SLOPE * e2;
        e3 = e3 >= 0.f ? e3 : NEG_SLOPE * e3;
        float w0 = __expf(e0);
        float w1 = (rem > 1) ? __expf(e1) : 0.f;
        float w2 = (rem > 2) ? __expf(e2) : 0.f;
        float w3 = (rem > 3) ? __expf(e3) : 0.f;

        short4v v0 = *(const short4v*)&h16[(size_t)s0 * C_OUT + ch0];
        short4v v1 = *(const short4v*)&h16[(size_t)s1 * C_OUT + ch0];
        short4v v2 = *(const short4v*)&h16[(size_t)s2 * C_OUT + ch0];
        short4v v3 = *(const short4v*)&h16[(size_t)s3 * C_OUT + ch0];

        auto bf2f = [](short v) { return __uint_as_float(((unsigned)(unsigned short)v) << 16); };
        a0 += w0 * bf2f(v0[0]) + w1 * bf2f(v1[0]) + w2 * bf2f(v2[0]) + w3 * bf2f(v3[0]);
        a1 += w0 * bf2f(v0[1]) + w1 * bf2f(v1[1]) + w2 * bf2f(v2[1]) + w3 * bf2f(v3[1]);
        a2 += w0 * bf2f(v0[2]) + w1 * bf2f(v1[2]) + w2 * bf2f(v2[2]) + w3 * bf2f(v3[2]);
        a3 += w0 * bf2f(v0[3]) + w1 * bf2f(v1[3]) + w2 * bf2f(v2[3]) + w3 * bf2f(v3[3]);
        den += w0 + w1 + w2 + w3;
    }

    float inv = 1.0f / (den + EPS_F);
    float4 b4 = *(const float4*)&bias[ch0];
    float4 o;
    o.x = a0 * inv + b4.x;
    o.y = a1 * inv + b4.y;
    o.z = a2 * inv + b4.z;
    o.w = a3 * inv + b4.w;
    *(float4*)&out[(size_t)n * C_OUT + ch0] = o;
}

// ---------------------------------------------------------------------------
extern "C" void kernel_launch(void* const* d_in, const int* in_sizes, int n_in,
                              void* d_out, int out_size, void* d_ws, size_t ws_size,
                              hipStream_t stream) {
    const float* x     = (const float*)d_in[0];
    const int*   eidx  = (const int*)d_in[1];
    const float* W     = (const float*)d_in[2];
    const float* a_src = (const float*)d_in[3];
    const float* a_dst = (const float*)d_in[4];
    const float* bias  = (const float*)d_in[5];
    float* out = (float*)d_out;

    const int* src = eidx;
    const int* dst = eidx + N_EDGES;

    char* p = (char*)d_ws;
    auto carve = [&](size_t bytes) {
        char* r = p;
        p += (bytes + 255) & ~(size_t)255;
        return r;
    };
    unsigned short* h16 = (unsigned short*)carve((size_t)N_NODES * C_OUT * 2); // 20.48 MB
    float* s_src      = (float*)carve((size_t)N_NODES * HEADS * 4);
    float* s_dst      = (float*)carve((size_t)N_NODES * HEADS * 4);
    int*   src_sorted = (int*)carve((size_t)N_EDGES * 4);
    int*   count      = (int*)carve((size_t)N_NODES * 4);
    int*   row_excl   = (int*)carve((size_t)N_NODES * 4);
    int*   cursor     = (int*)carve((size_t)N_NODES * 4);
    int*   btot       = (int*)carve(64 * 4);
    int*   boff       = (int*)carve(64 * 4);
    unsigned short* Bp = (unsigned short*)carve((size_t)131072 * 2);           // 256 KB

    hipMemsetAsync(count, 0, (size_t)N_NODES * 4, stream);

    pack_W<<<512, 256, 0, stream>>>(W, Bp);
    gemm_mfma<<<313, 512, 0, stream>>>(x, Bp, a_src, a_dst, h16, s_src, s_dst);
    count_edges<<<N_EDGES / 256, 256, 0, stream>>>(dst, count);
    scan_local<<<40, 1024, 0, stream>>>(count, row_excl, cursor, btot);
    scan_tots<<<1, 64, 0, stream>>>(btot, boff);
    scatter_edges<<<N_EDGES / 256, 256, 0, stream>>>(src, dst, cursor, boff, src_sorted);
    aggregate<<<N_NODES / 4, 256, 0, stream>>>(src_sorted, h16, s_src, s_dst,
                                               row_excl, boff, count, bias, out);
}